// Round 11
// baseline (624.028 us; speedup 1.0000x reference)
//
#include <hip/hip_runtime.h>
#include <hip/hip_bf16.h>

#define NTOK 8192
#define DIM 1024
#define NEXP 8
#define NT 512   // virtual K tiles: 16 segments (expert x half) x 32 tiles of BK=32
#define BK 32

typedef float f32x4 __attribute__((ext_vector_type(4)));
typedef short s16x8 __attribute__((ext_vector_type(8)));
typedef unsigned short u16;
typedef unsigned short u16x4 __attribute__((ext_vector_type(4)));

__device__ __forceinline__ u16 f2bf(float f) {
    __hip_bfloat16 h = __float2bfloat16(f);
    return *reinterpret_cast<u16*>(&h);
}
__device__ __forceinline__ float bf2f(u16 u) {
    unsigned v = ((unsigned)u) << 16;
    return __uint_as_float(v);
}

#define GLOAD16(gsrc, ldst)                                                     \
    __builtin_amdgcn_global_load_lds(                                           \
        (const __attribute__((address_space(1))) void*)(gsrc),                  \
        (__attribute__((address_space(3))) void*)(ldst), 16, 0, 0)

#define MFMA16(a, b, c) __builtin_amdgcn_mfma_f32_16x16x32_bf16((a), (b), (c), 0, 0, 0)
#define SGB() __builtin_amdgcn_sched_barrier(0)

// ---------------- gates: softmax(z_flat @ Wg^T + bg) -> gates[n][e] ----------
__global__ __launch_bounds__(256) void gates_kernel(
    const float* __restrict__ zr, const float* __restrict__ zi,
    const float* __restrict__ Wg, const float* __restrict__ bg,
    float* __restrict__ gates)
{
    const int wave = threadIdx.x >> 6, lane = threadIdx.x & 63;
    const int n = blockIdx.x * 4 + wave;

    float v[32];
    const float* zrp = zr + (size_t)n * DIM;
    const float* zip = zi + (size_t)n * DIM;
#pragma unroll
    for (int j = 0; j < 16; ++j) v[j] = zrp[j * 64 + lane];
#pragma unroll
    for (int j = 0; j < 16; ++j) v[16 + j] = zip[j * 64 + lane];

    float s[NEXP];
#pragma unroll
    for (int e = 0; e < NEXP; ++e) {
        const float* wrow = Wg + (size_t)e * (2 * DIM);
        float a = 0.f;
#pragma unroll
        for (int j = 0; j < 32; ++j) a += v[j] * wrow[j * 64 + lane];
#pragma unroll
        for (int m = 32; m; m >>= 1) a += __shfl_xor(a, m);
        s[e] = a + bg[e];
    }
    float mx = s[0];
#pragma unroll
    for (int e = 1; e < NEXP; ++e) mx = fmaxf(mx, s[e]);
    float p[NEXP], sum = 0.f;
#pragma unroll
    for (int e = 0; e < NEXP; ++e) { p[e] = expf(s[e] - mx); sum += p[e]; }
    const float inv = 1.f / sum;
    if (lane == 0) {
#pragma unroll
        for (int e = 0; e < NEXP; ++e) gates[(size_t)n * NEXP + e] = p[e] * inv;
    }
}

// ---------------- fp32 -> bf16 conversion (z and W) ----------------
__global__ __launch_bounds__(256) void cvt4_kernel(
    const float* __restrict__ zr, const float* __restrict__ zi,
    const float* __restrict__ Wr, const float* __restrict__ Wi,
    u16* __restrict__ zr16, u16* __restrict__ zi16,
    u16* __restrict__ Wr16, u16* __restrict__ Wi16)
{
    const size_t total = (size_t)NEXP * DIM * DIM / 4;
    for (size_t i = (size_t)blockIdx.x * 256 + threadIdx.x; i < total;
         i += (size_t)gridDim.x * 256) {
        f32x4 a = ((const f32x4*)zr)[i];
        f32x4 b = ((const f32x4*)zi)[i];
        f32x4 c = ((const f32x4*)Wr)[i];
        f32x4 d = ((const f32x4*)Wi)[i];
        u16x4 pa, pb, pc, pd;
#pragma unroll
        for (int j = 0; j < 4; ++j) {
            pa[j] = f2bf(a[j]); pb[j] = f2bf(b[j]);
            pc[j] = f2bf(c[j]); pd[j] = f2bf(d[j]);
        }
        ((u16x4*)zr16)[i] = pa;
        ((u16x4*)zi16)[i] = pb;
        ((u16x4*)Wr16)[i] = pc;
        ((u16x4*)Wi16)[i] = pd;
    }
}

// ---------------- main MoE GEMM: 128x256 tile, 256 thr, 2 blocks/CU ----------
// 4 waves (1M x 4N), per-wave 128x64, acc[8][4] = 128 VGPR. BK=32, NT=512.
// LDS 64 KB: A 2x8KB (VALU cvt from z16, gate*sign folded) + B 3x16KB
// (gload_lds for t+2). 2 blocks/CU (launch_bounds(256,2), VGPR<=256):
// each SIMD hosts 1 wave from each block -> when one block drains/barriers,
// the other issues MFMA (cross-block pipe overlap, m114).
// LDS layout both tiles: vrow v=row>>1 (64 elems), chunk cc=(row&1)*4+(k>>3),
// physical cc^=(v&7); inverse swizzle on global source (rule 21).
// r10 bug fixed: B staging slot ss = (sr+2)%3 was mis-branched (staged into
// the slot being READ when sr=0/1) -> now ss = (sr==0)?2:sr-1.
__global__ __launch_bounds__(256, 2) void moe_gemm11(
    const u16* __restrict__ zr16, const u16* __restrict__ zi16,
    const u16* __restrict__ Wr16, const u16* __restrict__ Wi16,
    const float* __restrict__ gates, float* __restrict__ out)
{
    extern __shared__ u16 lds[];  // A slots: 0, 4096 (elems); B: 8192 + s*8192

    // XCD map: xcd = bid&7 owns bm range [xcd*8, xcd*8+8) x all 8 (bn,sel).
    const int bid = blockIdx.x;
    const int xcd = bid & 7;
    const int loc = bid >> 3;           // 0..63
    const int grp = loc & 7;            // (bn,sel)
    const int bm = xcd * 8 + (loc >> 3);
    const int bn = grp & 3, sel = grp >> 2;

    const int tid = threadIdx.x;
    const int lane = tid & 63;
    const int wc = tid >> 6;   // 0..3 (N-split wave)

    // ---- A staging addressing (cvt path): thread t stages chunks 2t, 2t+1 ----
    int a_goff[2], gidx[2], a_loff[2];
#pragma unroll
    for (int q = 0; q < 2; ++q) {
        const int c = 2 * tid + q;          // 0..511
        const int v = c >> 3;
        const int ccl = (c & 7) ^ (v & 7);  // logical chunk
        const int row = 2 * v + (ccl >> 2);
        a_goff[q] = (bm * 128 + row) * DIM + (ccl & 3) * 8;
        gidx[q] = (bm * 128 + row) * NEXP;
        a_loff[q] = c * 8;                  // elems (physical, linear)
    }
    // ---- B staging addressing (gload path): instr q covers chunks q*256+t ----
    int b_goff[4];
#pragma unroll
    for (int q = 0; q < 4; ++q) {
        const int c = q * 256 + tid;        // 0..1023
        const int v = c >> 3;
        const int ccl = (c & 7) ^ (v & 7);
        b_goff[q] = (bn * 256 + 2 * v + (ccl >> 2)) * DIM + (ccl & 3) * 8;
    }

    // ---- fragment read addressing (elems) ----
    const int kg = lane >> 4;
    const int hl = (lane & 15) >> 1;
    const int abase = hl * 64 + ((((lane & 1) * 4 + kg) ^ hl) * 8);          // + m*512
    const int bbase = (wc * 32 + hl) * 64 + ((((lane & 1) * 4 + kg) ^ hl) * 8); // + n*512

    const int grow0 = bm * 128 + ((lane >> 4) << 2);

    f32x4 acc[8][4];
#pragma unroll
    for (int m = 0; m < 8; ++m)
#pragma unroll
        for (int n = 0; n < 4; ++n) acc[m][n] = (f32x4){0.f, 0.f, 0.f, 0.f};

    // ---- segment state: A tracks tile t+1, B tracks tile t+2 ----
    const u16* Asrc = sel ? zi16 : zr16;   // seg 0
    const u16* Bseg = Wr16;                // seg 0
    float sg[2];
#pragma unroll
    for (int q = 0; q < 2; ++q) sg[q] = gates[gidx[q]];

    // ---- prologue: A(0)->slot0 (cvt); B(0)->slot0, B(1)->slot1 (gloads) ----
    {
        s16x8 ga[2];
#pragma unroll
        for (int q = 0; q < 2; ++q) ga[q] = *(const s16x8*)(Asrc + a_goff[q]);
#pragma unroll
        for (int q = 0; q < 4; ++q) {
            GLOAD16(Bseg + b_goff[q], &lds[8192 + (q * 256 + tid) * 8]);
            GLOAD16(Bseg + b_goff[q] + BK, &lds[16384 + (q * 256 + tid) * 8]);
        }
#pragma unroll
        for (int q = 0; q < 2; ++q) {
            s16x8 w;
#pragma unroll
            for (int e = 0; e < 8; ++e)
                w[e] = (short)f2bf(bf2f((u16)ga[q][e]) * sg[q]);
            *(s16x8*)&lds[a_loff[q]] = w;
        }
        asm volatile("s_waitcnt vmcnt(4) lgkmcnt(0)" ::: "memory");  // B(0) done
        __builtin_amdgcn_s_barrier();
    }

    int sr = 0;  // B read slot = t%3
#pragma unroll 1
    for (int t = 0; t < NT; ++t) {
        const int tn1 = t + 1, tn2 = t + 2;
        if ((tn1 & 31) == 0) {  // A/gate state for t+1
            const int seg = tn1 >> 5;
            const int e = (seg >> 1) & 7;
            const int half = seg & 1;
            Asrc = (half ^ sel) ? zi16 : zr16;
            const float sgn = (sel == 0 && half == 1) ? -1.f : 1.f;
#pragma unroll
            for (int q = 0; q < 2; ++q) sg[q] = sgn * gates[gidx[q] + e];
        }
        if ((tn2 & 31) == 0) {  // B state for t+2
            const int seg = tn2 >> 5;
            const int e = (seg >> 1) & 7;
            Bseg = ((seg & 1) ? Wi16 : Wr16) + (size_t)e * DIM * DIM;
        }
        const int ka = (tn1 & 31) << 5;              // A staging k base (elems)
        const int kb = (tn2 & 31) << 5;              // B staging k base
        const int ss = (sr == 0) ? 2 : sr - 1;       // (t+2)%3  [r10 bug fixed]
        const int ab = ((t & 1) << 12) + abase;      // A read base (elems)
        const int bb = 8192 + sr * 8192 + bbase;     // B read base
        const int sa = (tn1 & 1) << 12;              // A staging dest
        const int sbB = 8192 + ss * 8192;            // B staging dest

        // ---- issue A reg-loads (t+1) FIRST, then B gloads (t+2) ----
        s16x8 ga[2];
#pragma unroll
        for (int q = 0; q < 2; ++q) ga[q] = *(const s16x8*)(Asrc + a_goff[q] + ka);
        GLOAD16(Bseg + b_goff[0] + kb, &lds[sbB + (0 * 256 + tid) * 8]);
        GLOAD16(Bseg + b_goff[1] + kb, &lds[sbB + (1 * 256 + tid) * 8]);
        GLOAD16(Bseg + b_goff[2] + kb, &lds[sbB + (2 * 256 + tid) * 8]);
        GLOAD16(Bseg + b_goff[3] + kb, &lds[sbB + (3 * 256 + tid) * 8]);

        // ---- fragment reads: B then A (m0..3), then A (m4..7) issue-ahead ----
        s16x8 bf[4], af[8];
#pragma unroll
        for (int n = 0; n < 4; ++n) bf[n] = *(const s16x8*)&lds[bb + n * 512];
#pragma unroll
        for (int m = 0; m < 4; ++m) af[m] = *(const s16x8*)&lds[ab + m * 512];
#pragma unroll
        for (int m = 4; m < 8; ++m) af[m] = *(const s16x8*)&lds[ab + m * 512];
        SGB();

        // ---- MFMA m0..3 (af4..7 reads drain underneath) ----
        __builtin_amdgcn_s_setprio(1);
#pragma unroll
        for (int m = 0; m < 4; ++m)
#pragma unroll
            for (int n = 0; n < 4; ++n) acc[m][n] = MFMA16(af[m], bf[n], acc[m][n]);
        __builtin_amdgcn_s_setprio(0);

        // ---- A cvt + writes (t+1) ----
#pragma unroll
        for (int q = 0; q < 2; ++q) {
            s16x8 w;
#pragma unroll
            for (int e = 0; e < 8; ++e)
                w[e] = (short)f2bf(bf2f((u16)ga[q][e]) * sg[q]);
            *(s16x8*)&lds[sa + a_loff[q]] = w;
        }

        // ---- MFMA m4..7 ----
        __builtin_amdgcn_s_setprio(1);
#pragma unroll
        for (int m = 4; m < 8; ++m)
#pragma unroll
            for (int n = 0; n < 4; ++n) acc[m][n] = MFMA16(af[m], bf[n], acc[m][n]);
        __builtin_amdgcn_s_setprio(0);

        // ---- tile end: counted vmcnt (B(t+2) in flight; B(t+1) already forced
        //      complete by the cvt's implicit wait on ga) + lgkm drain ----
        asm volatile("s_waitcnt vmcnt(4) lgkmcnt(0)" ::: "memory");
        __builtin_amdgcn_s_barrier();

        sr = (sr == 2) ? 0 : sr + 1;
    }
    asm volatile("s_waitcnt vmcnt(0)" ::: "memory");  // retire dead prefetches

    // ---- epilogue: C[row][col], col=lane&15, row=(lane>>4)*4+j (m89 layout) ----
    float* op = out + (size_t)sel * NTOK * DIM;
    const int col0 = bn * 256 + wc * 64 + (lane & 15);
#pragma unroll
    for (int m = 0; m < 8; ++m)
#pragma unroll
        for (int n = 0; n < 4; ++n)
#pragma unroll
            for (int j = 0; j < 4; ++j)
                op[(size_t)(grow0 + m * 16 + j) * DIM + col0 + n * 16] = acc[m][n][j];
}

extern "C" void kernel_launch(void* const* d_in, const int* in_sizes, int n_in,
                              void* d_out, int out_size, void* d_ws, size_t ws_size,
                              hipStream_t stream) {
    const float* zr = (const float*)d_in[0];
    const float* zi = (const float*)d_in[1];
    const float* Wg = (const float*)d_in[2];
    const float* bg = (const float*)d_in[3];
    const float* Wr = (const float*)d_in[4];
    const float* Wi = (const float*)d_in[5];
    float* out = (float*)d_out;

    const size_t NELEM = (size_t)NEXP * DIM * DIM;  // == NTOK*DIM
    u16* zr16 = (u16*)d_ws;
    u16* zi16 = zr16 + NELEM;
    u16* Wr16 = zi16 + NELEM;
    u16* Wi16 = Wr16 + NELEM;
    float* gates = (float*)(Wi16 + NELEM);

    cvt4_kernel<<<2048, 256, 0, stream>>>(zr, zi, Wr, Wi, zr16, zi16, Wr16, Wi16);
    gates_kernel<<<NTOK / 4, 256, 0, stream>>>(zr, zi, Wg, bg, gates);

    hipFuncSetAttribute((const void*)moe_gemm11,
                        hipFuncAttributeMaxDynamicSharedMemorySize, 131072);
    moe_gemm11<<<512, 256, 65536, stream>>>(zr16, zi16, Wr16, Wi16, gates, out);
}

// Round 12
// 550.761 us; speedup vs baseline: 1.1330x; 1.1330x over previous
//
#include <hip/hip_runtime.h>
#include <hip/hip_bf16.h>

#define NTOK 8192
#define DIM 1024
#define NEXP 8
#define NT 256   // virtual K tiles: 16 segments (expert x half) x 16 tiles of BK=64
#define BK 64

typedef float f32x4 __attribute__((ext_vector_type(4)));
typedef short s16x8 __attribute__((ext_vector_type(8)));
typedef unsigned short u16;
typedef unsigned short u16x4 __attribute__((ext_vector_type(4)));

__device__ __forceinline__ u16 f2bf(float f) {
    __hip_bfloat16 h = __float2bfloat16(f);
    return *reinterpret_cast<u16*>(&h);
}
__device__ __forceinline__ float bf2f(u16 u) {
    unsigned v = ((unsigned)u) << 16;
    return __uint_as_float(v);
}

#define GLOAD16(gsrc, ldst)                                                     \
    __builtin_amdgcn_global_load_lds(                                           \
        (const __attribute__((address_space(1))) void*)(gsrc),                  \
        (__attribute__((address_space(3))) void*)(ldst), 16, 0, 0)

#define MFMA16(a, b, c) __builtin_amdgcn_mfma_f32_16x16x32_bf16((a), (b), (c), 0, 0, 0)
#define SGB() __builtin_amdgcn_sched_barrier(0)

// ---------------- gates: softmax(z_flat @ Wg^T + bg) ----------------
__global__ __launch_bounds__(256) void gates_kernel(
    const float* __restrict__ zr, const float* __restrict__ zi,
    const float* __restrict__ Wg, const float* __restrict__ bg,
    float* __restrict__ gates)
{
    const int wave = threadIdx.x >> 6, lane = threadIdx.x & 63;
    const int n = blockIdx.x * 4 + wave;

    float v[32];
    const float* zrp = zr + (size_t)n * DIM;
    const float* zip = zi + (size_t)n * DIM;
#pragma unroll
    for (int j = 0; j < 16; ++j) v[j] = zrp[j * 64 + lane];
#pragma unroll
    for (int j = 0; j < 16; ++j) v[16 + j] = zip[j * 64 + lane];

    float s[NEXP];
#pragma unroll
    for (int e = 0; e < NEXP; ++e) {
        const float* wrow = Wg + (size_t)e * (2 * DIM);
        float a = 0.f;
#pragma unroll
        for (int j = 0; j < 32; ++j) a += v[j] * wrow[j * 64 + lane];
#pragma unroll
        for (int m = 32; m; m >>= 1) a += __shfl_xor(a, m);
        s[e] = a + bg[e];
    }
    float mx = s[0];
#pragma unroll
    for (int e = 1; e < NEXP; ++e) mx = fmaxf(mx, s[e]);
    float p[NEXP], sum = 0.f;
#pragma unroll
    for (int e = 0; e < NEXP; ++e) { p[e] = expf(s[e] - mx); sum += p[e]; }
    const float inv = 1.f / sum;
    if (lane == 0) {
#pragma unroll
        for (int e = 0; e < NEXP; ++e) gates[(size_t)n * NEXP + e] = p[e] * inv;
    }
}

// ---------------- fp32 -> bf16 conversion (z and W) ----------------
__global__ __launch_bounds__(256) void cvt4_kernel(
    const float* __restrict__ zr, const float* __restrict__ zi,
    const float* __restrict__ Wr, const float* __restrict__ Wi,
    u16* __restrict__ zr16, u16* __restrict__ zi16,
    u16* __restrict__ Wr16, u16* __restrict__ Wi16)
{
    const size_t total = (size_t)NEXP * DIM * DIM / 4;
    for (size_t i = (size_t)blockIdx.x * 256 + threadIdx.x; i < total;
         i += (size_t)gridDim.x * 256) {
        f32x4 a = ((const f32x4*)zr)[i];
        f32x4 b = ((const f32x4*)zi)[i];
        f32x4 c = ((const f32x4*)Wr)[i];
        f32x4 d = ((const f32x4*)Wi)[i];
        u16x4 pa, pb, pc, pd;
#pragma unroll
        for (int j = 0; j < 4; ++j) {
            pa[j] = f2bf(a[j]); pb[j] = f2bf(b[j]);
            pc[j] = f2bf(c[j]); pd[j] = f2bf(d[j]);
        }
        ((u16x4*)zr16)[i] = pa;
        ((u16x4*)zi16)[i] = pb;
        ((u16x4*)Wr16)[i] = pc;
        ((u16x4*)Wi16)[i] = pd;
    }
}

// ---------------- main MoE GEMM: 256x256, A-3deep pipelined ------------------
// 512 threads = 8 waves (2M x 4N), per-wave 128x64. Virtual K = 16 seg x 1024.
// LDS 160 KB: A 3x32KB (VALU cvt writes for t+2) + B 2x32KB (gload_lds t+1).
// A slot (t+1)%3 is STABLE during tile t -> next tile's a0 reads pre-issued
// BEFORE the barrier (drain under MFMA3+barrier); post-barrier head = b0 only.
// Tail wait vmcnt(0)+lgkmcnt(4): DS retires in-order and MFMA3's implicit a3
// wait already retired the cvt-writes, so only the 4 pre-issued reads stay in
// flight across the barrier. Swizzle/epilogue/XCD-map = r8 verbatim.
__global__ __launch_bounds__(512, 2) void moe_gemm12(
    const u16* __restrict__ zr16, const u16* __restrict__ zi16,
    const u16* __restrict__ Wr16, const u16* __restrict__ Wi16,
    const float* __restrict__ gates, float* __restrict__ out)
{
    extern __shared__ u16 lds[];  // A slots: 0,16384,32768; B slots: 49152,65536

    // bm-local XCD remap: hw xcd = linear%8 owns bm in [xcd*4, xcd*4+4).
    const int linear = blockIdx.x + 32 * (blockIdx.y + 4 * blockIdx.z);
    const int xcd = linear & 7;
    const int bm = xcd * 4 + ((linear >> 3) & 3);
    const int grp2 = linear >> 5;   // 0..7
    const int bn = grp2 & 3;
    const int sel = grp2 >> 2;

    const int tid = threadIdx.x;
    const int lane = tid & 63;
    const int wid = tid >> 6;
    const int wr = wid >> 2;   // 0..1
    const int wc = wid & 3;    // 0..3

    // ---- staging addressing (swizzle chunk c ^= row&7, inverse on source) ----
    const int srow = tid >> 3;
    const int schunk = (tid & 7) ^ (srow & 7);
    int arow[4], gidx[4], brow[4];
#pragma unroll
    for (int j = 0; j < 4; ++j) {
        const int gr = bm * 256 + srow + j * 64;
        arow[j] = gr * DIM + schunk * 8;
        gidx[j] = gr * NEXP;
        brow[j] = (bn * 256 + srow + j * 64) * DIM + schunk * 8;
    }

    // ---- fragment read addressing (elems) ----
    const int cg = lane >> 4;
    const int l7 = lane & 7;
    const int ach0 = (cg ^ l7) * 8;
    const int ach1 = ((4 + cg) ^ l7) * 8;
    const int arbase = (wr * 128 + (lane & 15)) * BK;
    const int brbase = (wc * 64 + (lane & 15)) * BK;

    f32x4 acc[8][4];
#pragma unroll
    for (int m = 0; m < 8; ++m)
#pragma unroll
        for (int n = 0; n < 4; ++n) acc[m][n] = (f32x4){0.f, 0.f, 0.f, 0.f};

    // ---- state: A/gates track tile t+2 (cvt-ahead); B tracks t+1 ----
    const u16* Asrc = sel ? zi16 : zr16;   // seg 0
    const u16* Bseg = Wr16;                // seg 0
    float sg[4];
#pragma unroll
    for (int j = 0; j < 4; ++j) sg[j] = gates[gidx[j]];

    // ---- prologue: cvt A(0)->slot0, A(1)->slot1; gload B(0)->bslot0 ----
    {
        s16x8 ga0[4], ga1[4];
#pragma unroll
        for (int j = 0; j < 4; ++j) {
            ga0[j] = *(const s16x8*)(Asrc + arow[j]);
            ga1[j] = *(const s16x8*)(Asrc + arow[j] + BK);
        }
#pragma unroll
        for (int q = 0; q < 4; ++q)
            GLOAD16(Bseg + brow[q], &lds[49152 + (q * 512 + tid) * 8]);
#pragma unroll
        for (int j = 0; j < 4; ++j) {
            s16x8 w0, w1;
#pragma unroll
            for (int e = 0; e < 8; ++e) {
                w0[e] = (short)f2bf(bf2f((u16)ga0[j][e]) * sg[j]);
                w1[e] = (short)f2bf(bf2f((u16)ga1[j][e]) * sg[j]);
            }
            *(s16x8*)&lds[(tid + j * 512) * 8] = w0;
            *(s16x8*)&lds[16384 + (tid + j * 512) * 8] = w1;
        }
        asm volatile("s_waitcnt vmcnt(0) lgkmcnt(0)" ::: "memory");
        __builtin_amdgcn_s_barrier();
    }

    // pre-issue a0 reads for tile 0 (slot 0)
    s16x8 a0p[4];
#pragma unroll
    for (int m = 0; m < 4; ++m)
        a0p[m] = *(const s16x8*)&lds[arbase + m * 1024 + ach0];

    int ars = 0;  // A read slot = t%3
    int aws = 2;  // A write slot = (t+2)%3
    int brs = 0;  // B read slot = t&1
#pragma unroll 1
    for (int t = 0; t < NT; ++t) {
        const int t1 = t + 1, t2 = t + 2;
        if ((t2 & 15) == 0) {  // A/gate state for tile t+2
            const int seg = t2 >> 4;
            const int e = (seg >> 1) & 7;
            const int half = seg & 1;
            Asrc = (half ^ sel) ? zi16 : zr16;
            const float sgn = (sel == 0 && half == 1) ? -1.f : 1.f;
#pragma unroll
            for (int j = 0; j < 4; ++j) sg[j] = sgn * gates[gidx[j] + e];
        }
        if ((t1 & 15) == 0) {  // B state for tile t+1
            const int seg = t1 >> 4;
            const int e = (seg >> 1) & 7;
            Bseg = ((seg & 1) ? Wi16 : Wr16) + (size_t)e * DIM * DIM;
        }
        const int ka = (t2 & 15) << 6;            // A staging k base (elems)
        const int kb = (t1 & 15) << 6;            // B staging k base
        const int ab = ars * 16384 + arbase;      // A read base
        const int bb = 49152 + brs * 16384 + brbase;  // B read base
        const int sa = aws * 16384;                   // A staging dest
        const int sbB = 49152 + (brs ^ 1) * 16384;    // B staging dest

        // ---- head: b0 reads (only post-barrier critical LDS) ----
        s16x8 b0[4];
#pragma unroll
        for (int n = 0; n < 4; ++n) b0[n] = *(const s16x8*)&lds[bb + n * 1024 + ach0];
        // ga(t+2) reg loads FIRST, then B(t+1) gloads (vmcnt ordering)
        s16x8 ga[4];
#pragma unroll
        for (int j = 0; j < 4; ++j) ga[j] = *(const s16x8*)(Asrc + arow[j] + ka);
        GLOAD16(Bseg + brow[0] + kb, &lds[sbB + (0 * 512 + tid) * 8]);
        GLOAD16(Bseg + brow[1] + kb, &lds[sbB + (1 * 512 + tid) * 8]);
        GLOAD16(Bseg + brow[2] + kb, &lds[sbB + (2 * 512 + tid) * 8]);
        GLOAD16(Bseg + brow[3] + kb, &lds[sbB + (3 * 512 + tid) * 8]);
        // a1 reads (ks0, m4-7)
        s16x8 a1[4];
#pragma unroll
        for (int m = 0; m < 4; ++m) a1[m] = *(const s16x8*)&lds[ab + (m + 4) * 1024 + ach0];
        SGB();
        __builtin_amdgcn_s_setprio(1);
#pragma unroll
        for (int m = 0; m < 4; ++m)
#pragma unroll
            for (int n = 0; n < 4; ++n) acc[m][n] = MFMA16(a0p[m], b0[n], acc[m][n]);
        __builtin_amdgcn_s_setprio(0);

        // ---- cvt chunks 0,1 -> slot aws; b1 + a2 reads ----
#pragma unroll
        for (int j = 0; j < 2; ++j) {
            s16x8 w;
#pragma unroll
            for (int e = 0; e < 8; ++e)
                w[e] = (short)f2bf(bf2f((u16)ga[j][e]) * sg[j]);
            *(s16x8*)&lds[sa + (tid + j * 512) * 8] = w;
        }
        s16x8 b1[4], a2[4];
#pragma unroll
        for (int n = 0; n < 4; ++n) b1[n] = *(const s16x8*)&lds[bb + n * 1024 + ach1];
#pragma unroll
        for (int m = 0; m < 4; ++m) a2[m] = *(const s16x8*)&lds[ab + m * 1024 + ach1];
        SGB();
        __builtin_amdgcn_s_setprio(1);
#pragma unroll
        for (int m = 0; m < 4; ++m)
#pragma unroll
            for (int n = 0; n < 4; ++n) acc[m + 4][n] = MFMA16(a1[m], b0[n], acc[m + 4][n]);
        __builtin_amdgcn_s_setprio(0);

        // ---- cvt chunks 2,3; a3 reads ----
#pragma unroll
        for (int j = 2; j < 4; ++j) {
            s16x8 w;
#pragma unroll
            for (int e = 0; e < 8; ++e)
                w[e] = (short)f2bf(bf2f((u16)ga[j][e]) * sg[j]);
            *(s16x8*)&lds[sa + (tid + j * 512) * 8] = w;
        }
        s16x8 a3[4];
#pragma unroll
        for (int m = 0; m < 4; ++m) a3[m] = *(const s16x8*)&lds[ab + (m + 4) * 1024 + ach1];
        SGB();
        __builtin_amdgcn_s_setprio(1);
#pragma unroll
        for (int m = 0; m < 4; ++m)
#pragma unroll
            for (int n = 0; n < 4; ++n) acc[m][n] = MFMA16(a2[m], b1[n], acc[m][n]);
        __builtin_amdgcn_s_setprio(0);

        // ---- pre-issue a0p for t+1 from slot (t+1)%3 (stable this tile) ----
        const int arn = (ars == 2) ? 0 : ars + 1;
        const int abn = arn * 16384 + arbase;
#pragma unroll
        for (int m = 0; m < 4; ++m) a0p[m] = *(const s16x8*)&lds[abn + m * 1024 + ach0];
        SGB();
        __builtin_amdgcn_s_setprio(1);
#pragma unroll
        for (int m = 0; m < 4; ++m)
#pragma unroll
            for (int n = 0; n < 4; ++n) acc[m + 4][n] = MFMA16(a3[m], b1[n], acc[m + 4][n]);
        __builtin_amdgcn_s_setprio(0);

        // ---- tail: B(t+1) gloads drained (issued early; free); cvt writes
        //      already retired by MFMA3's implicit a3 wait (in-order DS);
        //      lgkmcnt(4) keeps the 4 pre-issued a0p reads in flight ----
        asm volatile("s_waitcnt vmcnt(0) lgkmcnt(4)" ::: "memory");
        __builtin_amdgcn_s_barrier();

        ars = arn;
        aws = (aws == 2) ? 0 : aws + 1;
        brs ^= 1;
    }
    asm volatile("s_waitcnt vmcnt(0) lgkmcnt(0)" ::: "memory");

    // ---- epilogue: C[row][col], col=lane&15, row=(lane>>4)*4+j (m89 layout) ----
    float* op = out + (size_t)sel * NTOK * DIM;
    const int col0 = bn * 256 + wc * 64 + (lane & 15);
    const int row0 = bm * 256 + wr * 128 + ((lane >> 4) << 2);
#pragma unroll
    for (int m = 0; m < 8; ++m)
#pragma unroll
        for (int n = 0; n < 4; ++n)
#pragma unroll
            for (int j = 0; j < 4; ++j)
                op[(size_t)(row0 + m * 16 + j) * DIM + col0 + n * 16] = acc[m][n][j];
}

extern "C" void kernel_launch(void* const* d_in, const int* in_sizes, int n_in,
                              void* d_out, int out_size, void* d_ws, size_t ws_size,
                              hipStream_t stream) {
    const float* zr = (const float*)d_in[0];
    const float* zi = (const float*)d_in[1];
    const float* Wg = (const float*)d_in[2];
    const float* bg = (const float*)d_in[3];
    const float* Wr = (const float*)d_in[4];
    const float* Wi = (const float*)d_in[5];
    float* out = (float*)d_out;

    const size_t NELEM = (size_t)NEXP * DIM * DIM;  // == NTOK*DIM
    u16* zr16 = (u16*)d_ws;
    u16* zi16 = zr16 + NELEM;
    u16* Wr16 = zi16 + NELEM;
    u16* Wi16 = Wr16 + NELEM;
    float* gates = (float*)(Wi16 + NELEM);

    cvt4_kernel<<<2048, 256, 0, stream>>>(zr, zi, Wr, Wi, zr16, zi16, Wr16, Wi16);
    gates_kernel<<<NTOK / 4, 256, 0, stream>>>(zr, zi, Wg, bg, gates);

    hipFuncSetAttribute((const void*)moe_gemm12,
                        hipFuncAttributeMaxDynamicSharedMemorySize, 163840);
    dim3 grid(NTOK / 256, DIM / 256, 2);
    moe_gemm12<<<grid, 512, 163840, stream>>>(zr16, zi16, Wr16, Wi16, gates, out);
}